// Round 1
// baseline (111073.633 us; speedup 1.0000x reference)
//
#include <hip/hip_runtime.h>
#include <hip/hip_cooperative_groups.h>

namespace cg = cooperative_groups;

typedef short bf16x8 __attribute__((ext_vector_type(8)));
typedef float f32x4 __attribute__((ext_vector_type(4)));

#define DEV static __device__ __forceinline__

// ---------------- numeric helpers ----------------
DEV unsigned short f2bf(float f) {
  unsigned u = __float_as_uint(f);
  unsigned r = u + 0x7fffu + ((u >> 16) & 1u);
  return (unsigned short)(r >> 16);
}
DEV float bf2f(unsigned short h) { return __uint_as_float(((unsigned)h) << 16); }
DEV void f2hilo(float f, unsigned short& hi, unsigned short& lo) {
  hi = f2bf(f);
  lo = f2bf(f - bf2f(hi));
}
DEV float sigm(float x) { return 1.f / (1.f + __expf(-x)); }
DEV float tanh_(float x) {
  x = fminf(15.f, fmaxf(-15.f, x));
  float e = __expf(2.f * x);
  return (e - 1.f) / (e + 1.f);
}

// ---------------- workspace layout ----------------
// W region: ushort elements from ws base
constexpr size_t WE1 = 1024 * 352, WE2 = 1024 * 512, WE3 = 1024 * 512,
                 WD1 = 1024 * 768, WD2 = 1024 * 512, WD3 = 320 * 352,
                 WKEY = 256 * 256, WVAL = 256 * 256, WEMB = 256 * 96;
constexpr size_t E1HI = 0, E1LO = E1HI + WE1, E2HI = E1LO + WE1, E2LO = E2HI + WE2,
                 E3HI = E2LO + WE2, E3LO = E3HI + WE3, D1HI = E3LO + WE3, D1LO = D1HI + WD1,
                 D2HI = D1LO + WD1, D2LO = D2HI + WD2, D3HI = D2LO + WD2, D3LO = D3HI + WD3,
                 KHI = D3LO + WD3, KLO = KHI + WKEY, VHI = KLO + WKEY, VLO = VHI + WVAL,
                 EMHI = VLO + WVAL, EMLO = EMHI + WEMB, WTOT = EMLO + WEMB;

constexpr size_t XPAD_ELEMS = (size_t)400 * 64 * 96;
constexpr size_t XPAD_HI_B = WTOT * 2;
constexpr size_t XPAD_LO_B = XPAD_HI_B + XPAD_ELEMS * 2;
constexpr size_t STATE_B = XPAD_LO_B + XPAD_ELEMS * 2;

// state sub-offsets (bytes relative to st = ws + STATE_B); zeroed by memset
constexpr size_t H256_SZB = (size_t)2 * 2 * 64 * 256 * 2;  // [parity][hi/lo][64][256] ushort
constexpr size_t HE1 = 0, HE2 = H256_SZB, HE3 = 2 * H256_SZB, HD1 = 3 * H256_SZB,
                 HD2 = 4 * H256_SZB;
constexpr size_t HLAST = 5 * H256_SZB;                       // [2][2][64][96] ushort
constexpr size_t HLAST_SZB = (size_t)2 * 2 * 64 * 96 * 2;
constexpr size_t CBASE = HLAST + HLAST_SZB;
constexpr size_t C256 = (size_t)64 * 256 * 4;
constexpr size_t CE1 = CBASE, CE2 = CBASE + C256, CE3 = CBASE + 2 * C256,
                 CD1 = CBASE + 3 * C256, CD2 = CBASE + 4 * C256, CD3 = CBASE + 5 * C256;
constexpr size_t CD3_SZ = (size_t)64 * 80 * 4;
constexpr size_t STATE_BYTES = CD3 + CD3_SZ;

// non-zeroed extras
constexpr size_t RINGK_B = STATE_B + STATE_BYTES;
constexpr size_t RING_SZ = (size_t)20 * 64 * 256 * 4;
constexpr size_t RINGV_B = RINGK_B + RING_SZ;
constexpr size_t EMBH_B = RINGV_B + RING_SZ;
constexpr size_t EMBL_B = EMBH_B + (size_t)64 * 256 * 2;
constexpr size_t CTXH_B = EMBL_B + (size_t)64 * 256 * 2;
constexpr size_t CTXL_B = CTXH_B + (size_t)64 * 256 * 2;
constexpr size_t WS_NEED = CTXL_B + (size_t)64 * 256 * 2;

// ---------------- prep kernels ----------------
__global__ void prep_w(const float* __restrict__ wih, int din, const float* __restrict__ whh,
                       int dh, int rows, int dinp, int kp, unsigned short* __restrict__ whi,
                       unsigned short* __restrict__ wlo) {
  size_t idx = (size_t)blockIdx.x * 256 + threadIdx.x;
  size_t tot = (size_t)rows * kp;
  if (idx >= tot) return;
  int j = (int)(idx / kp), k = (int)(idx % kp);
  float v = 0.f;
  if (k < dinp) {
    if (k < din) v = wih[(size_t)j * din + k];
  } else {
    int k2 = k - dinp;
    if (k2 < dh) v = whh[(size_t)j * dh + k2];
  }
  unsigned short hi, lo;
  f2hilo(v, hi, lo);
  whi[idx] = hi;
  wlo[idx] = lo;
}

__global__ void prep_x(const float* __restrict__ x, unsigned short* __restrict__ xh,
                       unsigned short* __restrict__ xl) {
  size_t idx = (size_t)blockIdx.x * 256 + threadIdx.x;
  if (idx >= XPAD_ELEMS) return;
  int t = (int)(idx / 6144), rbf = (int)(idx % 6144), b = rbf / 96, f = rbf % 96;
  float v = (f < 80) ? x[(size_t)b * 32000 + (size_t)t * 80 + f] : 0.f;
  unsigned short hi, lo;
  f2hilo(v, hi, lo);
  xh[idx] = hi;
  xl[idx] = lo;
}

// ---------------- main kernel ----------------
struct Src {
  const unsigned short* hi;
  const unsigned short* lo;
  int kp;
};

DEV unsigned short* hbuf(unsigned char* st, size_t cellOff, int par, int hl, int Hpad) {
  return (unsigned short*)(st + cellOff) + (size_t)(par * 2 + hl) * 64 * Hpad;
}

DEV void mfma3(f32x4& acc, bf16x8 ah, bf16x8 al, bf16x8 bh, bf16x8 bl) {
  acc = __builtin_amdgcn_mfma_f32_16x16x32_bf16(ah, bh, acc, 0, 0, 0);
  acc = __builtin_amdgcn_mfma_f32_16x16x32_bf16(al, bh, acc, 0, 0, 0);
  acc = __builtin_amdgcn_mfma_f32_16x16x32_bf16(ah, bl, acc, 0, 0, 0);
}

// LSTM tile: one 16-unit column tile (ut), all 64 batches, all 4 gates.
template <int NSRC>
DEV void lstm_tile(int lane, int ut, int H, int Hpad, const Src (&srcs)[NSRC],
                   const unsigned short* __restrict__ Whi, const unsigned short* __restrict__ Wlo,
                   int Kp, const float* __restrict__ bias, float* __restrict__ c,
                   unsigned short* hwhi, unsigned short* hwlo, float* outp) {
  f32x4 acc[4][4];
#pragma unroll
  for (int g = 0; g < 4; g++)
#pragma unroll
    for (int m = 0; m < 4; m++) acc[g][m] = f32x4{0.f, 0.f, 0.f, 0.f};

  const int col = lane & 15, kg = lane >> 4;
  int kw = kg * 8;  // running k into W rows
#pragma unroll
  for (int s = 0; s < NSRC; s++) {
    const int kp = srcs[s].kp;
    const unsigned short* shi = srcs[s].hi;
    const unsigned short* slo = srcs[s].lo;
    for (int kb = 0; kb < kp; kb += 32) {
      const int ka = kb + kg * 8;
      bf16x8 ah[4], al[4];
#pragma unroll
      for (int m = 0; m < 4; m++) {
        int row = m * 16 + col;
        ah[m] = *(const bf16x8*)(shi + (size_t)row * kp + ka);
        al[m] = *(const bf16x8*)(slo + (size_t)row * kp + ka);
      }
#pragma unroll
      for (int g = 0; g < 4; g++) {
        int brow = g * H + ut * 16 + col;
        bf16x8 bh = *(const bf16x8*)(Whi + (size_t)brow * Kp + kw);
        bf16x8 bl = *(const bf16x8*)(Wlo + (size_t)brow * Kp + kw);
#pragma unroll
        for (int m = 0; m < 4; m++) mfma3(acc[g][m], ah[m], al[m], bh, bl);
      }
      kw += 32;
    }
  }
  // elementwise cell update (lane-local: all 4 gates of (b,u) share lane/reg)
  const int u = ut * 16 + col;
  const float bi = bias[u], bff = bias[H + u], bg = bias[2 * H + u], bo = bias[3 * H + u];
#pragma unroll
  for (int m = 0; m < 4; m++) {
#pragma unroll
    for (int r = 0; r < 4; r++) {
      int b = m * 16 + kg * 4 + r;
      float gi = acc[0][m][r] + bi;
      float gf = acc[1][m][r] + bff;
      float gg = acc[2][m][r] + bg;
      float go = acc[3][m][r] + bo;
      float cold = c[b * H + u];
      float cn = sigm(gf) * cold + sigm(gi) * tanh_(gg);
      float hh = sigm(go) * tanh_(cn);
      c[b * H + u] = cn;
      unsigned short hi, lo;
      f2hilo(hh, hi, lo);
      hwhi[b * Hpad + u] = hi;
      hwlo[b * Hpad + u] = lo;
      if (outp) outp[(size_t)b * 30400 + u] = hh;
    }
  }
}

// Linear tile: one 16-col tile (jt), all 64 batches, + bias.
DEV void linear_tile(int lane, int jt, const Src& src, const unsigned short* __restrict__ Whi,
                     const unsigned short* __restrict__ Wlo, int Kp, const float* __restrict__ bias,
                     float* out_f32, unsigned short* ohi, unsigned short* olo) {
  f32x4 acc[4];
#pragma unroll
  for (int m = 0; m < 4; m++) acc[m] = f32x4{0.f, 0.f, 0.f, 0.f};
  const int col = lane & 15, kg = lane >> 4;
  for (int kb = 0; kb < Kp; kb += 32) {
    int ka = kb + kg * 8;
    bf16x8 bh = *(const bf16x8*)(Whi + (size_t)(jt * 16 + col) * Kp + ka);
    bf16x8 bl = *(const bf16x8*)(Wlo + (size_t)(jt * 16 + col) * Kp + ka);
#pragma unroll
    for (int m = 0; m < 4; m++) {
      int row = m * 16 + col;
      bf16x8 ah = *(const bf16x8*)(src.hi + (size_t)row * src.kp + ka);
      bf16x8 al = *(const bf16x8*)(src.lo + (size_t)row * src.kp + ka);
      mfma3(acc[m], ah, al, bh, bl);
    }
  }
  int j = jt * 16 + col;
  float bj = bias[j];
#pragma unroll
  for (int m = 0; m < 4; m++)
#pragma unroll
    for (int r = 0; r < 4; r++) {
      int b = m * 16 + kg * 4 + r;
      float v = acc[m][r] + bj;
      if (out_f32) out_f32[(size_t)b * 256 + j] = v;
      if (ohi) {
        unsigned short hi, lo;
        f2hilo(v, hi, lo);
        ohi[b * 256 + j] = hi;
        olo[b * 256 + j] = lo;
      }
    }
}

// attention for one batch row b (whole wave)
DEV void attn_wave(int lane, int b, const unsigned short* qh, const unsigned short* ql,
                   const float* ringk, const float* ringv, unsigned short* ctxh,
                   unsigned short* ctxl) {
  float qv[4];
#pragma unroll
  for (int j = 0; j < 4; j++) {
    int e = lane + 64 * j;
    qv[j] = bf2f(qh[b * 256 + e]) + bf2f(ql[b * 256 + e]);
  }
  float s[20];
#pragma unroll
  for (int kk = 0; kk < 20; kk++) {
    const float* kr = ringk + ((size_t)kk * 64 + b) * 256;
    float part = 0.f;
#pragma unroll
    for (int j = 0; j < 4; j++) part += kr[lane + 64 * j] * qv[j];
#pragma unroll
    for (int off = 32; off; off >>= 1) part += __shfl_xor(part, off, 64);
    s[kk] = part;
  }
  float mx = s[0];
#pragma unroll
  for (int kk = 1; kk < 20; kk++) mx = fmaxf(mx, s[kk]);
  float den = 0.f;
#pragma unroll
  for (int kk = 0; kk < 20; kk++) {
    s[kk] = __expf(s[kk] - mx);
    den += s[kk];
  }
  float inv = 1.f / den;
#pragma unroll
  for (int j = 0; j < 4; j++) {
    int e = lane + 64 * j;
    float a = 0.f;
#pragma unroll
    for (int kk = 0; kk < 20; kk++) a += s[kk] * ringv[((size_t)kk * 64 + b) * 256 + e];
    a *= inv;
    unsigned short hi, lo;
    f2hilo(a, hi, lo);
    ctxh[b * 256 + e] = hi;
    ctxl[b * 256 + e] = lo;
  }
}

#define NWG 32
#define WGS 512

__global__ void __launch_bounds__(WGS, 1)
seq_main(const float* e1b, const float* e2b, const float* e3b, const float* d1b,
         const float* d2b, const float* d3b, const float* embb, const float* keyb,
         const float* valb, float* dout, unsigned char* ws) {
  cg::grid_group grid = cg::this_grid();
  const int wid = blockIdx.x * (WGS / 64) + (threadIdx.x >> 6);
  const int lane = threadIdx.x & 63;

  unsigned short* W = (unsigned short*)ws;
  const unsigned short* xh = (const unsigned short*)(ws + XPAD_HI_B);
  const unsigned short* xl = (const unsigned short*)(ws + XPAD_LO_B);
  unsigned char* st = ws + STATE_B;
  float* ringk = (float*)(ws + RINGK_B);
  float* ringv = (float*)(ws + RINGV_B);
  unsigned short* embh = (unsigned short*)(ws + EMBH_B);
  unsigned short* embl = (unsigned short*)(ws + EMBL_B);
  unsigned short* ctxh = (unsigned short*)(ws + CTXH_B);
  unsigned short* ctxl = (unsigned short*)(ws + CTXL_B);

  for (int t = 0; t < 400; ++t) {
    const int p = t & 1, q = p ^ 1;
    const int slot = t % 20;
    if (t < 21) {
      // ---------- encoder rhythm (phase 1 + t==20 encoder part) ----------
      if (wid < 16) {
        Src ss[2] = {{xh + (size_t)t * 6144, xl + (size_t)t * 6144, 96},
                     {hbuf(st, HE1, q, 0, 256), hbuf(st, HE1, q, 1, 256), 256}};
        lstm_tile(lane, wid, 256, 256, ss, W + E1HI, W + E1LO, 352, e1b, (float*)(st + CE1),
                  hbuf(st, HE1, p, 0, 256), hbuf(st, HE1, p, 1, 256), nullptr);
      }
      grid.sync();
      if (wid < 16) {
        Src ss[2] = {{hbuf(st, HE1, p, 0, 256), hbuf(st, HE1, p, 1, 256), 256},
                     {hbuf(st, HE2, q, 0, 256), hbuf(st, HE2, q, 1, 256), 256}};
        lstm_tile(lane, wid, 256, 256, ss, W + E2HI, W + E2LO, 512, e2b, (float*)(st + CE2),
                  hbuf(st, HE2, p, 0, 256), hbuf(st, HE2, p, 1, 256), nullptr);
      }
      grid.sync();
      if (wid < 16) {
        Src ss[2] = {{hbuf(st, HE2, p, 0, 256), hbuf(st, HE2, p, 1, 256), 256},
                     {hbuf(st, HE3, q, 0, 256), hbuf(st, HE3, q, 1, 256), 256}};
        lstm_tile(lane, wid, 256, 256, ss, W + E3HI, W + E3LO, 512, e3b, (float*)(st + CE3),
                  hbuf(st, HE3, p, 0, 256), hbuf(st, HE3, p, 1, 256), nullptr);
      }
      grid.sync();
      if (wid < 16) {
        Src s = {hbuf(st, HE3, p, 0, 256), hbuf(st, HE3, p, 1, 256), 256};
        linear_tile(lane, wid, s, W + KHI, W + KLO, 256, keyb, ringk + (size_t)slot * 64 * 256,
                    nullptr, nullptr);
      } else if (wid < 32) {
        Src s = {hbuf(st, HE3, p, 0, 256), hbuf(st, HE3, p, 1, 256), 256};
        linear_tile(lane, wid - 16, s, W + VHI, W + VLO, 256, valb,
                    ringv + (size_t)slot * 64 * 256, nullptr, nullptr);
      }
      grid.sync();
      if (t == 20) {
        // decoder bootstrap: emb(x19) + ctx=v20, then d1,d2,d3
        if (wid < 16) {
          Src s = {xh + (size_t)19 * 6144, xl + (size_t)19 * 6144, 96};
          linear_tile(lane, wid, s, W + EMHI, W + EMLO, 96, embb, nullptr, embh, embl);
        } else if (wid < 32) {
          int ib = (wid - 16) * 4;
          for (int bb = ib; bb < ib + 4; ++bb)
            for (int j = 0; j < 4; ++j) {
              int e = lane + 64 * j;
              float v = ringv[(size_t)bb * 256 + e];  // slot 0 holds v20
              unsigned short hi, lo;
              f2hilo(v, hi, lo);
              ctxh[bb * 256 + e] = hi;
              ctxl[bb * 256 + e] = lo;
            }
        }
        grid.sync();
        if (wid < 16) {
          Src ss[3] = {{embh, embl, 256},
                       {ctxh, ctxl, 256},
                       {hbuf(st, HD1, q, 0, 256), hbuf(st, HD1, q, 1, 256), 256}};
          lstm_tile(lane, wid, 256, 256, ss, W + D1HI, W + D1LO, 768, d1b, (float*)(st + CD1),
                    hbuf(st, HD1, p, 0, 256), hbuf(st, HD1, p, 1, 256), nullptr);
        }
        grid.sync();
        if (wid < 16) {
          Src ss[2] = {{hbuf(st, HD1, p, 0, 256), hbuf(st, HD1, p, 1, 256), 256},
                       {hbuf(st, HD2, q, 0, 256), hbuf(st, HD2, q, 1, 256), 256}};
          lstm_tile(lane, wid, 256, 256, ss, W + D2HI, W + D2LO, 512, d2b, (float*)(st + CD2),
                    hbuf(st, HD2, p, 0, 256), hbuf(st, HD2, p, 1, 256), nullptr);
        }
        grid.sync();
        if (wid < 5) {
          Src ss[2] = {{hbuf(st, HD2, p, 0, 256), hbuf(st, HD2, p, 1, 256), 256},
                       {hbuf(st, HLAST, q, 0, 96), hbuf(st, HLAST, q, 1, 96), 96}};
          lstm_tile(lane, wid, 80, 96, ss, W + D3HI, W + D3LO, 352, d3b, (float*)(st + CD3),
                    hbuf(st, HLAST, p, 0, 96), hbuf(st, HLAST, p, 1, 96), dout);
        }
        grid.sync();
      }
    } else {
      // ---------- phase 2 ----------
      // S1: e1 | emb | attn (all depend only on step t-1)
      if (wid < 16) {
        Src ss[2] = {{hbuf(st, HLAST, q, 0, 96), hbuf(st, HLAST, q, 1, 96), 96},
                     {hbuf(st, HE1, q, 0, 256), hbuf(st, HE1, q, 1, 256), 256}};
        lstm_tile(lane, wid, 256, 256, ss, W + E1HI, W + E1LO, 352, e1b, (float*)(st + CE1),
                  hbuf(st, HE1, p, 0, 256), hbuf(st, HE1, p, 1, 256), nullptr);
      } else if (wid < 32) {
        Src s = {hbuf(st, HLAST, q, 0, 96), hbuf(st, HLAST, q, 1, 96), 96};
        linear_tile(lane, wid - 16, s, W + EMHI, W + EMLO, 96, embb, nullptr, embh, embl);
      } else if (wid >= 64 && wid < 128) {
        attn_wave(lane, wid - 64, hbuf(st, HD2, q, 0, 256), hbuf(st, HD2, q, 1, 256), ringk,
                  ringv, ctxh, ctxl);
      }
      grid.sync();
      // S2: e2 | d1
      if (wid < 16) {
        Src ss[2] = {{hbuf(st, HE1, p, 0, 256), hbuf(st, HE1, p, 1, 256), 256},
                     {hbuf(st, HE2, q, 0, 256), hbuf(st, HE2, q, 1, 256), 256}};
        lstm_tile(lane, wid, 256, 256, ss, W + E2HI, W + E2LO, 512, e2b, (float*)(st + CE2),
                  hbuf(st, HE2, p, 0, 256), hbuf(st, HE2, p, 1, 256), nullptr);
      } else if (wid < 32) {
        Src ss[3] = {{embh, embl, 256},
                     {ctxh, ctxl, 256},
                     {hbuf(st, HD1, q, 0, 256), hbuf(st, HD1, q, 1, 256), 256}};
        lstm_tile(lane, wid - 16, 256, 256, ss, W + D1HI, W + D1LO, 768, d1b, (float*)(st + CD1),
                  hbuf(st, HD1, p, 0, 256), hbuf(st, HD1, p, 1, 256), nullptr);
      }
      grid.sync();
      // S3: e3 | d2
      if (wid < 16) {
        Src ss[2] = {{hbuf(st, HE2, p, 0, 256), hbuf(st, HE2, p, 1, 256), 256},
                     {hbuf(st, HE3, q, 0, 256), hbuf(st, HE3, q, 1, 256), 256}};
        lstm_tile(lane, wid, 256, 256, ss, W + E3HI, W + E3LO, 512, e3b, (float*)(st + CE3),
                  hbuf(st, HE3, p, 0, 256), hbuf(st, HE3, p, 1, 256), nullptr);
      } else if (wid < 32) {
        Src ss[2] = {{hbuf(st, HD1, p, 0, 256), hbuf(st, HD1, p, 1, 256), 256},
                     {hbuf(st, HD2, q, 0, 256), hbuf(st, HD2, q, 1, 256), 256}};
        lstm_tile(lane, wid - 16, 256, 256, ss, W + D2HI, W + D2LO, 512, d2b, (float*)(st + CD2),
                  hbuf(st, HD2, p, 0, 256), hbuf(st, HD2, p, 1, 256), nullptr);
      }
      grid.sync();
      // S4: key | val | d3 (output + last)
      if (wid < 16) {
        Src s = {hbuf(st, HE3, p, 0, 256), hbuf(st, HE3, p, 1, 256), 256};
        linear_tile(lane, wid, s, W + KHI, W + KLO, 256, keyb, ringk + (size_t)slot * 64 * 256,
                    nullptr, nullptr);
      } else if (wid < 32) {
        Src s = {hbuf(st, HE3, p, 0, 256), hbuf(st, HE3, p, 1, 256), 256};
        linear_tile(lane, wid - 16, s, W + VHI, W + VLO, 256, valb,
                    ringv + (size_t)slot * 64 * 256, nullptr, nullptr);
      } else if (wid < 37) {
        Src ss[2] = {{hbuf(st, HD2, p, 0, 256), hbuf(st, HD2, p, 1, 256), 256},
                     {hbuf(st, HLAST, q, 0, 96), hbuf(st, HLAST, q, 1, 96), 96}};
        lstm_tile(lane, wid - 32, 80, 96, ss, W + D3HI, W + D3LO, 352, d3b, (float*)(st + CD3),
                  hbuf(st, HLAST, p, 0, 96), hbuf(st, HLAST, p, 1, 96),
                  dout + (size_t)(t - 20) * 80);
      }
      grid.sync();
    }
  }
}

// ---------------- launch ----------------
extern "C" void kernel_launch(void* const* d_in, const int* in_sizes, int n_in, void* d_out,
                              int out_size, void* d_ws, size_t ws_size, hipStream_t stream) {
  if (ws_size < WS_NEED) return;  // insufficient scratch; fail loudly (wrong output)

  const float* x = (const float*)d_in[0];
  const float* embW = (const float*)d_in[1];
  const float* embB = (const float*)d_in[2];
  const float* e1Wih = (const float*)d_in[3];
  const float* e1Whh = (const float*)d_in[4];
  const float* e1B = (const float*)d_in[5];
  const float* e2Wih = (const float*)d_in[6];
  const float* e2Whh = (const float*)d_in[7];
  const float* e2B = (const float*)d_in[8];
  const float* e3Wih = (const float*)d_in[9];
  const float* e3Whh = (const float*)d_in[10];
  const float* e3B = (const float*)d_in[11];
  const float* d1Wih = (const float*)d_in[12];
  const float* d1Whh = (const float*)d_in[13];
  const float* d1B = (const float*)d_in[14];
  const float* d2Wih = (const float*)d_in[15];
  const float* d2Whh = (const float*)d_in[16];
  const float* d2B = (const float*)d_in[17];
  const float* d3Wih = (const float*)d_in[18];
  const float* d3Whh = (const float*)d_in[19];
  const float* d3B = (const float*)d_in[20];
  const float* keyW = (const float*)d_in[21];
  const float* keyB = (const float*)d_in[22];
  const float* valW = (const float*)d_in[23];
  const float* valB = (const float*)d_in[24];

  unsigned char* ws = (unsigned char*)d_ws;
  unsigned short* W = (unsigned short*)ws;
  float* doutf = (float*)d_out;

  auto launch_w = [&](const float* wih, int din, const float* whh, int dh, int rows, int dinp,
                      int kp, size_t offhi, size_t offlo) {
    size_t tot = (size_t)rows * kp;
    int blocks = (int)((tot + 255) / 256);
    prep_w<<<blocks, 256, 0, stream>>>(wih, din, whh, dh, rows, dinp, kp, W + offhi, W + offlo);
  };
  launch_w(e1Wih, 80, e1Whh, 256, 1024, 96, 352, E1HI, E1LO);
  launch_w(e2Wih, 256, e2Whh, 256, 1024, 256, 512, E2HI, E2LO);
  launch_w(e3Wih, 256, e3Whh, 256, 1024, 256, 512, E3HI, E3LO);
  launch_w(d1Wih, 512, d1Whh, 256, 1024, 512, 768, D1HI, D1LO);
  launch_w(d2Wih, 256, d2Whh, 256, 1024, 256, 512, D2HI, D2LO);
  launch_w(d3Wih, 256, d3Whh, 80, 320, 256, 352, D3HI, D3LO);
  launch_w(keyW, 256, nullptr, 0, 256, 256, 256, KHI, KLO);
  launch_w(valW, 256, nullptr, 0, 256, 256, 256, VHI, VLO);
  launch_w(embW, 80, nullptr, 0, 256, 96, 96, EMHI, EMLO);
  prep_x<<<(int)((XPAD_ELEMS + 255) / 256), 256, 0, stream>>>(
      x, (unsigned short*)(ws + XPAD_HI_B), (unsigned short*)(ws + XPAD_LO_B));
  hipMemsetAsync(ws + STATE_B, 0, STATE_BYTES, stream);

  void* args[] = {(void*)&e1B,  (void*)&e2B,  (void*)&e3B, (void*)&d1B, (void*)&d2B,
                  (void*)&d3B,  (void*)&embB, (void*)&keyB, (void*)&valB,
                  (void*)&doutf, (void*)&ws};
  hipLaunchCooperativeKernel((void*)seq_main, dim3(NWG), dim3(WGS), args, 0, stream);
}